// Round 5
// baseline (235.694 us; speedup 1.0000x reference)
//
#include <hip/hip_runtime.h>
#include <hip/hip_bf16.h>

typedef __attribute__((ext_vector_type(8))) short short8;
typedef __attribute__((ext_vector_type(4))) short s16x4;
typedef __attribute__((ext_vector_type(4))) float f32x4;

// fp32 -> bf16 bits, round-to-nearest-even
static __device__ inline short f2bf(float f) {
    unsigned u = __float_as_uint(f);
    unsigned r = (u + 0x7fffu + ((u >> 16) & 1u)) >> 16;
    return (short)r;
}
static __device__ inline float bf2f(short h) {
    return __uint_as_float(((unsigned)(unsigned short)h) << 16);
}

// Swizzled LDS short-offset for 32-short (64B) rows; 16B slot in 0..3.
static __device__ inline int swz32(int row, int slot) {
    return row * 32 + ((slot ^ ((row >> 1) & 3)) << 3);
}
// For 64-short (128B) rows; 16B slot in 0..7.
static __device__ inline int swz64(int row, int slot) {
    return row * 64 + ((slot ^ (row & 7)) << 3);
}

// Normalize each row of vectors -> V (fp32)
__global__ __launch_bounds__(256) void k_normalize(const float* __restrict__ vec,
                                                   float* __restrict__ V, int dim) {
    int row = blockIdx.x;
    const float4* src = (const float4*)(vec + (size_t)row * dim);
    float4* dst = (float4*)(V + (size_t)row * dim);
    int nv4 = dim >> 2;
    float ss = 0.f;
    for (int i = threadIdx.x; i < nv4; i += blockDim.x) {
        float4 v = src[i];
        ss += v.x * v.x + v.y * v.y + v.z * v.z + v.w * v.w;
    }
    for (int off = 32; off; off >>= 1) ss += __shfl_down(ss, off, 64);
    __shared__ float ws_[4];
    int lane = threadIdx.x & 63, w = threadIdx.x >> 6;
    if (lane == 0) ws_[w] = ss;
    __syncthreads();
    float inv = 1.0f / sqrtf(ws_[0] + ws_[1] + ws_[2] + ws_[3]);
    for (int i = threadIdx.x; i < nv4; i += blockDim.x) {
        float4 v = src[i];
        v.x *= inv; v.y *= inv; v.z *= inv; v.w *= inv;
        dst[i] = v;
    }
}

// fp32 -> (hi, lo) bf16 split, elementwise
__global__ __launch_bounds__(256) void k_split(const float* __restrict__ X,
                                               short* __restrict__ Xh,
                                               short* __restrict__ Xl, int n4) {
    for (int i = blockIdx.x * blockDim.x + threadIdx.x; i < n4; i += gridDim.x * blockDim.x) {
        float4 v = ((const float4*)X)[i];
        float f[4] = {v.x, v.y, v.z, v.w};
        s16x4 h, l;
#pragma unroll
        for (int q = 0; q < 4; ++q) {
            h[q] = f2bf(f[q]);
            l[q] = f2bf(f[q] - bf2f(h[q]));
        }
        *(s16x4*)&Xh[(size_t)i * 4] = h;
        *(s16x4*)&Xl[(size_t)i * 4] = l;
    }
}

// fp32 -> bf16 (hi only), elementwise
__global__ __launch_bounds__(256) void k_cast(const float* __restrict__ X,
                                              short* __restrict__ Xh, int n4) {
    for (int i = blockIdx.x * blockDim.x + threadIdx.x; i < n4; i += gridDim.x * blockDim.x) {
        float4 v = ((const float4*)X)[i];
        float f[4] = {v.x, v.y, v.z, v.w};
        s16x4 h;
#pragma unroll
        for (int q = 0; q < 4; ++q) h[q] = f2bf(f[q]);
        *(s16x4*)&Xh[(size_t)i * 4] = h;
    }
}

// transpose + split: X (R x C, fp32) -> Xth, Xtl (C x R, bf16)
__global__ __launch_bounds__(256) void k_tsplit(const float* __restrict__ X,
                                                short* __restrict__ Xth,
                                                short* __restrict__ Xtl, int R, int C) {
    __shared__ float tile[32][33];
    int c0 = blockIdx.x * 32, r0 = blockIdx.y * 32;
    int t = threadIdx.x;
    int r = t >> 3, c4 = (t & 7) * 4;
    float4 v = *(const float4*)&X[(size_t)(r0 + r) * C + c0 + c4];
    tile[r][c4 + 0] = v.x; tile[r][c4 + 1] = v.y;
    tile[r][c4 + 2] = v.z; tile[r][c4 + 3] = v.w;
    __syncthreads();
    int rr = t >> 3, cc4 = (t & 7) * 4;
    s16x4 h, l;
#pragma unroll
    for (int q = 0; q < 4; ++q) {
        float f = tile[cc4 + q][rr];
        h[q] = f2bf(f);
        l[q] = f2bf(f - bf2f(h[q]));
    }
    *(s16x4*)&Xth[(size_t)(c0 + rr) * R + r0 + cc4] = h;
    *(s16x4*)&Xtl[(size_t)(c0 + rr) * R + r0 + cc4] = l;
}

// 128x128-tile NT GEMM with split-bf16 operands via global_load_lds (BK=32).
// C[i][j] = sum_k A[i][k]*B[j][k], acc = Ah*Bh + Ah*Bl + Al*Bh.
// MODE 1: split-write Ch/Cl.  MODE 2: Ch = bf16(delta - acc).  MODE 3: Cf + Ch/Cl.
// TRI 0: full K.  TRI 1: K-bound = j0+128 (B rows triangular).  TRI 2: skip j0<i0.
template<int MODE, int TRI>
__global__ __launch_bounds__(256) void k_nt128(
    const short* __restrict__ Ah, const short* __restrict__ Al,
    const short* __restrict__ Bh, const short* __restrict__ Bl,
    float* __restrict__ Cf, short* __restrict__ Ch, short* __restrict__ Cl,
    int K, int lda, int ldb, int ldc) {
    __shared__ short Ash[128 * 32];  // 8 KB each, 32 KB total
    __shared__ short Asl[128 * 32];
    __shared__ short Bsh[128 * 32];
    __shared__ short Bsl[128 * 32];
    int i0 = blockIdx.y * 128, j0 = blockIdx.x * 128;
    if (TRI == 2 && j0 < i0) return;
    int KE = (TRI == 1) ? (j0 + 128) : K;
    int t = threadIdx.x, lane = t & 63, wave = t >> 6;
    int wr = wave >> 1, wc = wave & 1;
    // staging: lane -> row lane>>2 within 16-row group, 16B slot lane&3;
    // source slot pre-swizzled so linear LDS dest yields swz32 layout (rule 21)
    int srIn = lane >> 2;
    int sslot = (lane & 3) ^ ((lane >> 3) & 3);
    f32x4 acc[4][4] = {};
    for (int k0 = 0; k0 < KE; k0 += 32) {
        __syncthreads();
#pragma unroll
        for (int q = 0; q < 2; ++q) {
            int rg = wave * 2 + q;          // 16-row group 0..7
            int row = rg * 16 + srIn;
            size_t ga = (size_t)(i0 + row) * lda + k0 + sslot * 8;
            size_t gb = (size_t)(j0 + row) * ldb + k0 + sslot * 8;
            __builtin_amdgcn_global_load_lds(
                (const __attribute__((address_space(1))) void*)&Ah[ga],
                (__attribute__((address_space(3))) void*)&Ash[rg * 16 * 32], 16, 0, 0);
            __builtin_amdgcn_global_load_lds(
                (const __attribute__((address_space(1))) void*)&Al[ga],
                (__attribute__((address_space(3))) void*)&Asl[rg * 16 * 32], 16, 0, 0);
            __builtin_amdgcn_global_load_lds(
                (const __attribute__((address_space(1))) void*)&Bh[gb],
                (__attribute__((address_space(3))) void*)&Bsh[rg * 16 * 32], 16, 0, 0);
            __builtin_amdgcn_global_load_lds(
                (const __attribute__((address_space(1))) void*)&Bl[gb],
                (__attribute__((address_space(3))) void*)&Bsl[rg * 16 * 32], 16, 0, 0);
        }
        __syncthreads();
        int g = lane >> 4;
        short8 ah[4], al2[4], bh[4], bl2[4];
#pragma unroll
        for (int i = 0; i < 4; ++i) {
            int ro = swz32(wr * 64 + i * 16 + (lane & 15), g);
            ah[i] = *(const short8*)&Ash[ro];
            al2[i] = *(const short8*)&Asl[ro];
        }
#pragma unroll
        for (int j = 0; j < 4; ++j) {
            int ro = swz32(wc * 64 + j * 16 + (lane & 15), g);
            bh[j] = *(const short8*)&Bsh[ro];
            bl2[j] = *(const short8*)&Bsl[ro];
        }
#pragma unroll
        for (int i = 0; i < 4; ++i)
#pragma unroll
            for (int j = 0; j < 4; ++j) {
                acc[i][j] = __builtin_amdgcn_mfma_f32_16x16x32_bf16(ah[i], bh[j], acc[i][j], 0, 0, 0);
                acc[i][j] = __builtin_amdgcn_mfma_f32_16x16x32_bf16(ah[i], bl2[j], acc[i][j], 0, 0, 0);
                acc[i][j] = __builtin_amdgcn_mfma_f32_16x16x32_bf16(al2[i], bh[j], acc[i][j], 0, 0, 0);
            }
    }
#pragma unroll
    for (int i = 0; i < 4; ++i)
#pragma unroll
        for (int j = 0; j < 4; ++j) {
            int row0 = i0 + wr * 64 + i * 16 + ((lane >> 4) << 2);
            int col = j0 + wc * 64 + j * 16 + (lane & 15);
#pragma unroll
            for (int r = 0; r < 4; ++r) {
                float v = acc[i][j][r];
                size_t idx = (size_t)(row0 + r) * ldc + col;
                if (MODE == 2) {
                    Ch[idx] = f2bf((((row0 + r) == col) ? 1.f : 0.f) - v);
                } else {
                    short h = f2bf(v);
                    short l = f2bf(v - bf2f(h));
                    Ch[idx] = h;
                    Cl[idx] = l;
                    if (MODE == 3) Cf[idx] = v;
                }
            }
        }
}

// Parallel inversion of 64x64 diagonal blocks of R = 0.5 I + striu(G).
__global__ __launch_bounds__(256) void k_baseinv2(const float* __restrict__ G,
                                                  short* __restrict__ Th, short* __restrict__ Tl,
                                                  short* __restrict__ Tth, short* __restrict__ Ttl,
                                                  int m) {
    __shared__ float Rs[64 * 64];
    int d = blockIdx.x >> 4, g = blockIdx.x & 15;
    int b0 = d * 64;
    int t = threadIdx.x, lane = t & 63, wave = t >> 6;
    {
        int r = t >> 2, c00 = (t & 3) * 16;
#pragma unroll
        for (int q = 0; q < 4; ++q)
            *(float4*)&Rs[r * 64 + c00 + q * 4] =
                *(const float4*)&G[(size_t)(b0 + r) * m + b0 + c00 + q * 4];
    }
    __syncthreads();
    int c = g * 4 + wave;
    float x = 0.f;
    for (int r = c; r >= 0; --r) {
        float prod = Rs[r * 64 + lane] * x;
        float s = prod;
#pragma unroll
        for (int off = 32; off; off >>= 1) s += __shfl_xor(s, off, 64);
        if (lane == r) x = ((r == c) ? 2.f : 0.f) - 2.f * s;
    }
    short h = f2bf(x);
    short l = f2bf(x - bf2f(h));
    Th[(size_t)(b0 + lane) * m + b0 + c] = h;
    Tl[(size_t)(b0 + lane) * m + b0 + c] = l;
    Tth[(size_t)(b0 + c) * m + b0 + lane] = h;
    Ttl[(size_t)(b0 + c) * m + b0 + lane] = l;
}

// Tree-level block GEMMs on split operands (NT MFMA, triangular K-bounds).
template<int PHASE>
__global__ __launch_bounds__(256) void k_trimm(
    const short* __restrict__ Ah, const short* __restrict__ Al,
    const short* __restrict__ Bh, const short* __restrict__ Bl,
    short* __restrict__ C1h, short* __restrict__ C1l,
    short* __restrict__ C2h, short* __restrict__ C2l,
    int m, int s) {
    __shared__ short As[2][64 * 32];
    __shared__ short Bs[2][64 * 32];
    int p = blockIdx.z;
    int a0 = 2 * p * s, c0 = a0 + s;
    int r0 = blockIdx.y * 64, ct = blockIdx.x * 64;
    int KS = (PHASE == 1) ? 0 : r0;
    int KE = (PHASE == 1) ? (ct + 64) : s;
    size_t tbase = (size_t)p * s * s;
    int t = threadIdx.x, lane = t & 63, wave = t >> 6;
    int wr = wave >> 1, wc = wave & 1;
    int srow = t >> 2, slot = t & 3;
    int sofs = swz32(srow, slot);
    int gofs = slot * 8;
    f32x4 acc[2][2] = {};
    for (int k0 = KS; k0 < KE; k0 += 32) {
        __syncthreads();
        if (PHASE == 1) {
            *(short8*)&As[0][sofs] = *(const short8*)&Ah[(size_t)(a0 + r0 + srow) * m + c0 + k0 + gofs];
            *(short8*)&As[1][sofs] = *(const short8*)&Al[(size_t)(a0 + r0 + srow) * m + c0 + k0 + gofs];
            *(short8*)&Bs[0][sofs] = *(const short8*)&Bh[(size_t)(c0 + ct + srow) * m + c0 + k0 + gofs];
            *(short8*)&Bs[1][sofs] = *(const short8*)&Bl[(size_t)(c0 + ct + srow) * m + c0 + k0 + gofs];
        } else {
            *(short8*)&As[0][sofs] = *(const short8*)&Ah[(size_t)(a0 + r0 + srow) * m + a0 + k0 + gofs];
            *(short8*)&As[1][sofs] = *(const short8*)&Al[(size_t)(a0 + r0 + srow) * m + a0 + k0 + gofs];
            *(short8*)&Bs[0][sofs] = *(const short8*)&Bh[tbase + (size_t)(ct + srow) * s + k0 + gofs];
            *(short8*)&Bs[1][sofs] = *(const short8*)&Bl[tbase + (size_t)(ct + srow) * s + k0 + gofs];
        }
        __syncthreads();
        int g = lane >> 4;
        short8 ah[2], al2[2], bh[2], bl2[2];
#pragma unroll
        for (int i = 0; i < 2; ++i) {
            int ro = swz32(wr * 32 + i * 16 + (lane & 15), g);
            ah[i] = *(const short8*)&As[0][ro];
            al2[i] = *(const short8*)&As[1][ro];
        }
#pragma unroll
        for (int j = 0; j < 2; ++j) {
            int ro = swz32(wc * 32 + j * 16 + (lane & 15), g);
            bh[j] = *(const short8*)&Bs[0][ro];
            bl2[j] = *(const short8*)&Bs[1][ro];
        }
#pragma unroll
        for (int i = 0; i < 2; ++i)
#pragma unroll
            for (int j = 0; j < 2; ++j) {
                acc[i][j] = __builtin_amdgcn_mfma_f32_16x16x32_bf16(ah[i], bh[j], acc[i][j], 0, 0, 0);
                acc[i][j] = __builtin_amdgcn_mfma_f32_16x16x32_bf16(ah[i], bl2[j], acc[i][j], 0, 0, 0);
                acc[i][j] = __builtin_amdgcn_mfma_f32_16x16x32_bf16(al2[i], bh[j], acc[i][j], 0, 0, 0);
            }
    }
#pragma unroll
    for (int i = 0; i < 2; ++i)
#pragma unroll
        for (int j = 0; j < 2; ++j) {
            int row0 = r0 + wr * 32 + i * 16 + ((lane >> 4) << 2);
            int col = ct + wc * 32 + j * 16 + (lane & 15);
#pragma unroll
            for (int r = 0; r < 4; ++r) {
                if (PHASE == 1) {
                    float v = acc[i][j][r];
                    short h = f2bf(v);
                    short l = f2bf(v - bf2f(h));
                    size_t idx = tbase + (size_t)col * s + row0 + r;
                    C1h[idx] = h;
                    C1l[idx] = l;
                } else {
                    float v = -acc[i][j][r];
                    short h = f2bf(v);
                    short l = f2bf(v - bf2f(h));
                    int R = a0 + row0 + r, Cc = c0 + col;
                    C1h[(size_t)R * m + Cc] = h;
                    C1l[(size_t)R * m + Cc] = l;
                    C2h[(size_t)Cc * m + R] = h;
                    C2l[(size_t)Cc * m + R] = l;
                }
            }
        }
}

// out = xh * Qt^T + bias.  128x128 tile, BK=64, global_load_lds, XCD-swizzled grid:
// same-XCD blocks cover all 8 col-tiles of consecutive row-panels -> x panel + Qt
// stay in that XCD's L2 (panel 256KB x 8 + Qt 2MB ~= 4MB).
__global__ __launch_bounds__(256) void k_apply3(const short* __restrict__ xh,
                                                const short* __restrict__ Qt,
                                                const float* __restrict__ bias,
                                                float* __restrict__ out, int dim) {
    __shared__ short As[128 * 64];
    __shared__ short Bs[128 * 64];
    int nwg = gridDim.x * gridDim.y;
    int flat = blockIdx.y * gridDim.x + blockIdx.x;
    int cpx = nwg >> 3;
    int L = (flat & 7) * cpx + (flat >> 3);   // bijective: nwg % 8 == 0
    int m0 = (L / gridDim.x) * 128, n0 = (L % gridDim.x) * 128;
    int t = threadIdx.x, lane = t & 63, wave = t >> 6;
    int wr = wave >> 1, wc = wave & 1;
    int sr = lane >> 3;
    int sslot = (lane & 7) ^ (sr & 7);
    f32x4 acc[4][4] = {};
    for (int k0 = 0; k0 < dim; k0 += 64) {
        __syncthreads();
#pragma unroll
        for (int q = 0; q < 4; ++q) {
            int rg = wave * 4 + q;
            int row = rg * 8 + sr;
            const short* gA = &xh[(size_t)(m0 + row) * dim + k0 + sslot * 8];
            const short* gB = &Qt[(size_t)(n0 + row) * dim + k0 + sslot * 8];
            __builtin_amdgcn_global_load_lds(
                (const __attribute__((address_space(1))) void*)gA,
                (__attribute__((address_space(3))) void*)&As[rg * 8 * 64], 16, 0, 0);
            __builtin_amdgcn_global_load_lds(
                (const __attribute__((address_space(1))) void*)gB,
                (__attribute__((address_space(3))) void*)&Bs[rg * 8 * 64], 16, 0, 0);
        }
        __syncthreads();
#pragma unroll
        for (int kk = 0; kk < 2; ++kk) {
            int g = kk * 4 + (lane >> 4);
            short8 af[4], bf_[4];
#pragma unroll
            for (int i = 0; i < 4; ++i)
                af[i] = *(const short8*)&As[swz64(wr * 64 + i * 16 + (lane & 15), g)];
#pragma unroll
            for (int j = 0; j < 4; ++j)
                bf_[j] = *(const short8*)&Bs[swz64(wc * 64 + j * 16 + (lane & 15), g)];
#pragma unroll
            for (int i = 0; i < 4; ++i)
#pragma unroll
                for (int j = 0; j < 4; ++j)
                    acc[i][j] = __builtin_amdgcn_mfma_f32_16x16x32_bf16(af[i], bf_[j], acc[i][j], 0, 0, 0);
        }
    }
#pragma unroll
    for (int i = 0; i < 4; ++i)
#pragma unroll
        for (int j = 0; j < 4; ++j) {
            int row = m0 + wr * 64 + i * 16 + (lane >> 4) * 4;
            int col = n0 + wc * 64 + j * 16 + (lane & 15);
            float b = bias[col];
#pragma unroll
            for (int r = 0; r < 4; ++r)
                out[(size_t)(row + r) * dim + col] = acc[i][j][r] + b;
        }
}

extern "C" void kernel_launch(void* const* d_in, const int* in_sizes, int n_in,
                              void* d_out, int out_size, void* d_ws, size_t ws_size,
                              hipStream_t stream) {
    const float* x = (const float*)d_in[0];
    const float* vec = (const float*)d_in[1];
    const float* bias = (const float*)d_in[2];
    float* out = (float*)d_out;

    int dim = in_sizes[2];
    int m = in_sizes[1] / dim;
    int n = in_sizes[0] / dim;

    const size_t MD = (size_t)m * dim;
    const size_t MM = (size_t)m * m;

    char* cur = (char*)d_ws;
    auto alloc_f = [&](size_t nelem) { float* p = (float*)cur; cur += nelem * 4; return p; };
    auto alloc_s = [&](size_t nelem) { short* p = (short*)cur; cur += nelem * 2; return p; };
    float* V   = alloc_f(MD);
    float* G   = alloc_f(MM);
    short* Vh  = alloc_s(MD);
    short* Vl  = alloc_s(MD);
    short* Vth = alloc_s(MD);
    short* Vtl = alloc_s(MD);
    short* Gh  = alloc_s(MM);
    short* Gl  = alloc_s(MM);
    short* Th  = alloc_s(MM);
    short* Tl  = alloc_s(MM);
    short* Tth = alloc_s(MM);
    short* Ttl = alloc_s(MM);
    short* Wh  = alloc_s(MD);
    short* Wl  = alloc_s(MD);
    short* Qt  = alloc_s((size_t)dim * dim);
    short* tmph = alloc_s(MM / 2);
    short* tmpl = alloc_s(MM / 2);
    short* xh  = alloc_s((size_t)n * dim);

    k_normalize<<<m, 256, 0, stream>>>(vec, V, dim);
    k_split<<<1024, 256, 0, stream>>>(V, Vh, Vl, (int)(MD / 4));
    k_tsplit<<<dim3(dim / 32, m / 32), 256, 0, stream>>>(V, Vth, Vtl, m, dim);

    // G = V * V^T, upper-triangle 128-tiles; fp32 + split outputs
    k_nt128<3, 2><<<dim3(m / 128, m / 128), 256, 0, stream>>>(Vh, Vl, Vh, Vl, G, Gh, Gl,
                                                              dim, dim, dim, m);
    // diag-block inversion -> split T (row-major + transposed)
    k_baseinv2<<<(m / 64) * 16, 256, 0, stream>>>(G, Th, Tl, Tth, Ttl, m);
    // tree levels, all MFMA on split operands
    for (int s = 64; s < m; s <<= 1) {
        dim3 g(s / 64, s / 64, m / (2 * s));
        k_trimm<1><<<g, 256, 0, stream>>>(Gh, Gl, Tth, Ttl, tmph, tmpl, nullptr, nullptr, m, s);
        k_trimm<2><<<g, 256, 0, stream>>>(Th, Tl, tmph, tmpl, Th, Tl, Tth, Ttl, m, s);
    }

    // W[d][k] = sum_{j<=k} Vt[d][j] * Tt[k][j]  (triangular K-bound)
    k_nt128<1, 1><<<dim3(m / 128, dim / 128), 256, 0, stream>>>(Vth, Vtl, Tth, Ttl, nullptr, Wh, Wl,
                                                                m, m, m, m);
    // Qt[e][d] = delta - sum_k Vt[e][k] * W[d][k]
    k_nt128<2, 0><<<dim3(dim / 128, dim / 128), 256, 0, stream>>>(Vth, Vtl, Wh, Wl, nullptr, Qt, nullptr,
                                                                  m, m, m, dim);

    // xh = bf16(x); out = xh * Qt^T + bias
    k_cast<<<2048, 256, 0, stream>>>(x, xh, (int)((size_t)n * dim / 4));
    k_apply3<<<dim3(dim / 128, n / 128), 256, 0, stream>>>(xh, Qt, bias, out, dim);
}

// Round 6
// 167.058 us; speedup vs baseline: 1.4109x; 1.4109x over previous
//
#include <hip/hip_runtime.h>
#include <hip/hip_bf16.h>

typedef __attribute__((ext_vector_type(8))) short short8;
typedef __attribute__((ext_vector_type(4))) short s16x4;
typedef __attribute__((ext_vector_type(4))) float f32x4;

// fp32 -> bf16 bits, round-to-nearest-even
static __device__ inline short f2bf(float f) {
    unsigned u = __float_as_uint(f);
    unsigned r = (u + 0x7fffu + ((u >> 16) & 1u)) >> 16;
    return (short)r;
}
static __device__ inline float bf2f(short h) {
    return __uint_as_float(((unsigned)(unsigned short)h) << 16);
}

// Swizzled LDS short-offset for 32-short (64B) rows; 16B slot in 0..3.
static __device__ inline int swz32(int row, int slot) {
    return row * 32 + ((slot ^ ((row >> 1) & 3)) << 3);
}
// For 64-short (128B) rows; 16B slot in 0..7.
static __device__ inline int swz64(int row, int slot) {
    return row * 64 + ((slot ^ (row & 7)) << 3);
}

// Normalize each row of vectors -> V (fp32)
__global__ __launch_bounds__(256) void k_normalize(const float* __restrict__ vec,
                                                   float* __restrict__ V, int dim) {
    int row = blockIdx.x;
    const float4* src = (const float4*)(vec + (size_t)row * dim);
    float4* dst = (float4*)(V + (size_t)row * dim);
    int nv4 = dim >> 2;
    float ss = 0.f;
    for (int i = threadIdx.x; i < nv4; i += blockDim.x) {
        float4 v = src[i];
        ss += v.x * v.x + v.y * v.y + v.z * v.z + v.w * v.w;
    }
    for (int off = 32; off; off >>= 1) ss += __shfl_down(ss, off, 64);
    __shared__ float ws_[4];
    int lane = threadIdx.x & 63, w = threadIdx.x >> 6;
    if (lane == 0) ws_[w] = ss;
    __syncthreads();
    float inv = 1.0f / sqrtf(ws_[0] + ws_[1] + ws_[2] + ws_[3]);
    for (int i = threadIdx.x; i < nv4; i += blockDim.x) {
        float4 v = src[i];
        v.x *= inv; v.y *= inv; v.z *= inv; v.w *= inv;
        dst[i] = v;
    }
}

// fp32 -> (hi, lo) bf16 split, elementwise
__global__ __launch_bounds__(256) void k_split(const float* __restrict__ X,
                                               short* __restrict__ Xh,
                                               short* __restrict__ Xl, int n4) {
    for (int i = blockIdx.x * blockDim.x + threadIdx.x; i < n4; i += gridDim.x * blockDim.x) {
        float4 v = ((const float4*)X)[i];
        float f[4] = {v.x, v.y, v.z, v.w};
        s16x4 h, l;
#pragma unroll
        for (int q = 0; q < 4; ++q) {
            h[q] = f2bf(f[q]);
            l[q] = f2bf(f[q] - bf2f(h[q]));
        }
        *(s16x4*)&Xh[(size_t)i * 4] = h;
        *(s16x4*)&Xl[(size_t)i * 4] = l;
    }
}

// fp32 -> bf16 (hi only), elementwise
__global__ __launch_bounds__(256) void k_cast(const float* __restrict__ X,
                                              short* __restrict__ Xh, int n4) {
    for (int i = blockIdx.x * blockDim.x + threadIdx.x; i < n4; i += gridDim.x * blockDim.x) {
        float4 v = ((const float4*)X)[i];
        float f[4] = {v.x, v.y, v.z, v.w};
        s16x4 h;
#pragma unroll
        for (int q = 0; q < 4; ++q) h[q] = f2bf(f[q]);
        *(s16x4*)&Xh[(size_t)i * 4] = h;
    }
}

// transpose + split: X (R x C, fp32) -> Xth, Xtl (C x R, bf16)
__global__ __launch_bounds__(256) void k_tsplit(const float* __restrict__ X,
                                                short* __restrict__ Xth,
                                                short* __restrict__ Xtl, int R, int C) {
    __shared__ float tile[32][33];
    int c0 = blockIdx.x * 32, r0 = blockIdx.y * 32;
    int t = threadIdx.x;
    int r = t >> 3, c4 = (t & 7) * 4;
    float4 v = *(const float4*)&X[(size_t)(r0 + r) * C + c0 + c4];
    tile[r][c4 + 0] = v.x; tile[r][c4 + 1] = v.y;
    tile[r][c4 + 2] = v.z; tile[r][c4 + 3] = v.w;
    __syncthreads();
    int rr = t >> 3, cc4 = (t & 7) * 4;
    s16x4 h, l;
#pragma unroll
    for (int q = 0; q < 4; ++q) {
        float f = tile[cc4 + q][rr];
        h[q] = f2bf(f);
        l[q] = f2bf(f - bf2f(h[q]));
    }
    *(s16x4*)&Xth[(size_t)(c0 + rr) * R + r0 + cc4] = h;
    *(s16x4*)&Xtl[(size_t)(c0 + rr) * R + r0 + cc4] = l;
}

// 64x64-tile NT GEMM with split-bf16 operands and register-prefetch double
// buffering: issue next K-tile global loads at iter top; compute current from
// LDS buf[cur]; ds_write buf[cur^1] after compute. One barrier per iter, so
// global latency overlaps ds_read+MFMA (latency-bound regime: 1 block/CU).
// MODE 1: split-write Ch/Cl.  MODE 2: Ch = bf16(delta - acc).  MODE 3: Cf + Ch/Cl.
// TRI 0: full K.  TRI 1: K-bound = j0+64 (B rows triangular).  TRI 2: skip j0<i0.
template<int MODE, int TRI>
__global__ __launch_bounds__(256) void k_nt64p(
    const short* __restrict__ Ah, const short* __restrict__ Al,
    const short* __restrict__ Bh, const short* __restrict__ Bl,
    float* __restrict__ Cf, short* __restrict__ Ch, short* __restrict__ Cl,
    int K, int lda, int ldb, int ldc) {
    __shared__ short As[2][2][64 * 32];   // [dbuf][h/l], 16 KB
    __shared__ short Bs[2][2][64 * 32];   // 16 KB
    int i0 = blockIdx.y * 64, j0 = blockIdx.x * 64;
    if (TRI == 2 && j0 < i0) return;
    int KE = (TRI == 1) ? (j0 + 64) : K;
    int t = threadIdx.x, lane = t & 63, wave = t >> 6;
    int wr = wave >> 1, wc = wave & 1;
    int srow = t >> 2, slot = t & 3;
    int sofs = swz32(srow, slot);
    int gofs = slot * 8;
    const short* gA_h = &Ah[(size_t)(i0 + srow) * lda + gofs];
    const short* gA_l = &Al[(size_t)(i0 + srow) * lda + gofs];
    const short* gB_h = &Bh[(size_t)(j0 + srow) * ldb + gofs];
    const short* gB_l = &Bl[(size_t)(j0 + srow) * ldb + gofs];
    // prefetch tile 0 and stage it
    short8 pAh = *(const short8*)&gA_h[0];
    short8 pAl = *(const short8*)&gA_l[0];
    short8 pBh = *(const short8*)&gB_h[0];
    short8 pBl = *(const short8*)&gB_l[0];
    *(short8*)&As[0][0][sofs] = pAh;
    *(short8*)&As[0][1][sofs] = pAl;
    *(short8*)&Bs[0][0][sofs] = pBh;
    *(short8*)&Bs[0][1][sofs] = pBl;
    f32x4 acc[2][2] = {};
    int nIter = KE >> 5;
    int cur = 0;
    for (int it = 0; it < nIter; ++it) {
        __syncthreads();           // buf[cur] ready; buf[cur^1] fully consumed
        int kn = (it + 1) << 5;
        bool have = kn < KE;
        if (have) {                // issue next-tile loads; latency hides under MFMA
            pAh = *(const short8*)&gA_h[kn];
            pAl = *(const short8*)&gA_l[kn];
            pBh = *(const short8*)&gB_h[kn];
            pBl = *(const short8*)&gB_l[kn];
        }
        int g = lane >> 4;
        short8 ah[2], al2[2], bh[2], bl2[2];
#pragma unroll
        for (int i = 0; i < 2; ++i) {
            int ro = swz32(wr * 32 + i * 16 + (lane & 15), g);
            ah[i] = *(const short8*)&As[cur][0][ro];
            al2[i] = *(const short8*)&As[cur][1][ro];
        }
#pragma unroll
        for (int j = 0; j < 2; ++j) {
            int ro = swz32(wc * 32 + j * 16 + (lane & 15), g);
            bh[j] = *(const short8*)&Bs[cur][0][ro];
            bl2[j] = *(const short8*)&Bs[cur][1][ro];
        }
#pragma unroll
        for (int i = 0; i < 2; ++i)
#pragma unroll
            for (int j = 0; j < 2; ++j) {
                acc[i][j] = __builtin_amdgcn_mfma_f32_16x16x32_bf16(ah[i], bh[j], acc[i][j], 0, 0, 0);
                acc[i][j] = __builtin_amdgcn_mfma_f32_16x16x32_bf16(ah[i], bl2[j], acc[i][j], 0, 0, 0);
                acc[i][j] = __builtin_amdgcn_mfma_f32_16x16x32_bf16(al2[i], bh[j], acc[i][j], 0, 0, 0);
            }
        if (have) {                // stage next tile into the other buffer
            *(short8*)&As[cur ^ 1][0][sofs] = pAh;
            *(short8*)&As[cur ^ 1][1][sofs] = pAl;
            *(short8*)&Bs[cur ^ 1][0][sofs] = pBh;
            *(short8*)&Bs[cur ^ 1][1][sofs] = pBl;
        }
        cur ^= 1;
    }
#pragma unroll
    for (int i = 0; i < 2; ++i)
#pragma unroll
        for (int j = 0; j < 2; ++j) {
            int row0 = i0 + wr * 32 + i * 16 + ((lane >> 4) << 2);
            int col = j0 + wc * 32 + j * 16 + (lane & 15);
#pragma unroll
            for (int r = 0; r < 4; ++r) {
                float v = acc[i][j][r];
                size_t idx = (size_t)(row0 + r) * ldc + col;
                if (MODE == 2) {
                    Ch[idx] = f2bf((((row0 + r) == col) ? 1.f : 0.f) - v);
                } else {
                    short h = f2bf(v);
                    short l = f2bf(v - bf2f(h));
                    Ch[idx] = h;
                    Cl[idx] = l;
                    if (MODE == 3) Cf[idx] = v;
                }
            }
        }
}

// Parallel inversion of 64x64 diagonal blocks of R = 0.5 I + striu(G).
__global__ __launch_bounds__(256) void k_baseinv2(const float* __restrict__ G,
                                                  short* __restrict__ Th, short* __restrict__ Tl,
                                                  short* __restrict__ Tth, short* __restrict__ Ttl,
                                                  int m) {
    __shared__ float Rs[64 * 64];
    int d = blockIdx.x >> 4, g = blockIdx.x & 15;
    int b0 = d * 64;
    int t = threadIdx.x, lane = t & 63, wave = t >> 6;
    {
        int r = t >> 2, c00 = (t & 3) * 16;
#pragma unroll
        for (int q = 0; q < 4; ++q)
            *(float4*)&Rs[r * 64 + c00 + q * 4] =
                *(const float4*)&G[(size_t)(b0 + r) * m + b0 + c00 + q * 4];
    }
    __syncthreads();
    int c = g * 4 + wave;
    float x = 0.f;
    for (int r = c; r >= 0; --r) {
        float prod = Rs[r * 64 + lane] * x;
        float s = prod;
#pragma unroll
        for (int off = 32; off; off >>= 1) s += __shfl_xor(s, off, 64);
        if (lane == r) x = ((r == c) ? 2.f : 0.f) - 2.f * s;
    }
    short h = f2bf(x);
    short l = f2bf(x - bf2f(h));
    Th[(size_t)(b0 + lane) * m + b0 + c] = h;
    Tl[(size_t)(b0 + lane) * m + b0 + c] = l;
    Tth[(size_t)(b0 + c) * m + b0 + lane] = h;
    Ttl[(size_t)(b0 + c) * m + b0 + lane] = l;
}

// Tree-level block GEMMs on split operands (NT MFMA, triangular K-bounds).
template<int PHASE>
__global__ __launch_bounds__(256) void k_trimm(
    const short* __restrict__ Ah, const short* __restrict__ Al,
    const short* __restrict__ Bh, const short* __restrict__ Bl,
    short* __restrict__ C1h, short* __restrict__ C1l,
    short* __restrict__ C2h, short* __restrict__ C2l,
    int m, int s) {
    __shared__ short As[2][64 * 32];
    __shared__ short Bs[2][64 * 32];
    int p = blockIdx.z;
    int a0 = 2 * p * s, c0 = a0 + s;
    int r0 = blockIdx.y * 64, ct = blockIdx.x * 64;
    int KS = (PHASE == 1) ? 0 : r0;
    int KE = (PHASE == 1) ? (ct + 64) : s;
    size_t tbase = (size_t)p * s * s;
    int t = threadIdx.x, lane = t & 63, wave = t >> 6;
    int wr = wave >> 1, wc = wave & 1;
    int srow = t >> 2, slot = t & 3;
    int sofs = swz32(srow, slot);
    int gofs = slot * 8;
    f32x4 acc[2][2] = {};
    for (int k0 = KS; k0 < KE; k0 += 32) {
        __syncthreads();
        if (PHASE == 1) {
            *(short8*)&As[0][sofs] = *(const short8*)&Ah[(size_t)(a0 + r0 + srow) * m + c0 + k0 + gofs];
            *(short8*)&As[1][sofs] = *(const short8*)&Al[(size_t)(a0 + r0 + srow) * m + c0 + k0 + gofs];
            *(short8*)&Bs[0][sofs] = *(const short8*)&Bh[(size_t)(c0 + ct + srow) * m + c0 + k0 + gofs];
            *(short8*)&Bs[1][sofs] = *(const short8*)&Bl[(size_t)(c0 + ct + srow) * m + c0 + k0 + gofs];
        } else {
            *(short8*)&As[0][sofs] = *(const short8*)&Ah[(size_t)(a0 + r0 + srow) * m + a0 + k0 + gofs];
            *(short8*)&As[1][sofs] = *(const short8*)&Al[(size_t)(a0 + r0 + srow) * m + a0 + k0 + gofs];
            *(short8*)&Bs[0][sofs] = *(const short8*)&Bh[tbase + (size_t)(ct + srow) * s + k0 + gofs];
            *(short8*)&Bs[1][sofs] = *(const short8*)&Bl[tbase + (size_t)(ct + srow) * s + k0 + gofs];
        }
        __syncthreads();
        int g = lane >> 4;
        short8 ah[2], al2[2], bh[2], bl2[2];
#pragma unroll
        for (int i = 0; i < 2; ++i) {
            int ro = swz32(wr * 32 + i * 16 + (lane & 15), g);
            ah[i] = *(const short8*)&As[0][ro];
            al2[i] = *(const short8*)&As[1][ro];
        }
#pragma unroll
        for (int j = 0; j < 2; ++j) {
            int ro = swz32(wc * 32 + j * 16 + (lane & 15), g);
            bh[j] = *(const short8*)&Bs[0][ro];
            bl2[j] = *(const short8*)&Bs[1][ro];
        }
#pragma unroll
        for (int i = 0; i < 2; ++i)
#pragma unroll
            for (int j = 0; j < 2; ++j) {
                acc[i][j] = __builtin_amdgcn_mfma_f32_16x16x32_bf16(ah[i], bh[j], acc[i][j], 0, 0, 0);
                acc[i][j] = __builtin_amdgcn_mfma_f32_16x16x32_bf16(ah[i], bl2[j], acc[i][j], 0, 0, 0);
                acc[i][j] = __builtin_amdgcn_mfma_f32_16x16x32_bf16(al2[i], bh[j], acc[i][j], 0, 0, 0);
            }
    }
#pragma unroll
    for (int i = 0; i < 2; ++i)
#pragma unroll
        for (int j = 0; j < 2; ++j) {
            int row0 = r0 + wr * 32 + i * 16 + ((lane >> 4) << 2);
            int col = ct + wc * 32 + j * 16 + (lane & 15);
#pragma unroll
            for (int r = 0; r < 4; ++r) {
                if (PHASE == 1) {
                    float v = acc[i][j][r];
                    short h = f2bf(v);
                    short l = f2bf(v - bf2f(h));
                    size_t idx = tbase + (size_t)col * s + row0 + r;
                    C1h[idx] = h;
                    C1l[idx] = l;
                } else {
                    float v = -acc[i][j][r];
                    short h = f2bf(v);
                    short l = f2bf(v - bf2f(h));
                    int R = a0 + row0 + r, Cc = c0 + col;
                    C1h[(size_t)R * m + Cc] = h;
                    C1l[(size_t)R * m + Cc] = l;
                    C2h[(size_t)Cc * m + R] = h;
                    C2l[(size_t)Cc * m + R] = l;
                }
            }
        }
}

// out = xh * Qt^T + bias.  128x128 tile, BK=64, global_load_lds, XCD-swizzled grid:
// same-XCD blocks cover all 8 col-tiles of 8 consecutive row-panels -> x panel
// (2MB) + Qt (2MB) stay in that XCD's L2.
__global__ __launch_bounds__(256) void k_apply3(const short* __restrict__ xh,
                                                const short* __restrict__ Qt,
                                                const float* __restrict__ bias,
                                                float* __restrict__ out, int dim) {
    __shared__ short As[128 * 64];
    __shared__ short Bs[128 * 64];
    int nwg = gridDim.x * gridDim.y;
    int flat = blockIdx.y * gridDim.x + blockIdx.x;
    int cpx = nwg >> 3;
    int L = (flat & 7) * cpx + (flat >> 3);   // bijective: nwg % 8 == 0
    int m0 = (L / gridDim.x) * 128, n0 = (L % gridDim.x) * 128;
    int t = threadIdx.x, lane = t & 63, wave = t >> 6;
    int wr = wave >> 1, wc = wave & 1;
    int sr = lane >> 3;
    int sslot = (lane & 7) ^ (sr & 7);
    f32x4 acc[4][4] = {};
    for (int k0 = 0; k0 < dim; k0 += 64) {
        __syncthreads();
#pragma unroll
        for (int q = 0; q < 4; ++q) {
            int rg = wave * 4 + q;
            int row = rg * 8 + sr;
            const short* gA = &xh[(size_t)(m0 + row) * dim + k0 + sslot * 8];
            const short* gB = &Qt[(size_t)(n0 + row) * dim + k0 + sslot * 8];
            __builtin_amdgcn_global_load_lds(
                (const __attribute__((address_space(1))) void*)gA,
                (__attribute__((address_space(3))) void*)&As[rg * 8 * 64], 16, 0, 0);
            __builtin_amdgcn_global_load_lds(
                (const __attribute__((address_space(1))) void*)gB,
                (__attribute__((address_space(3))) void*)&Bs[rg * 8 * 64], 16, 0, 0);
        }
        __syncthreads();
#pragma unroll
        for (int kk = 0; kk < 2; ++kk) {
            int g = kk * 4 + (lane >> 4);
            short8 af[4], bf_[4];
#pragma unroll
            for (int i = 0; i < 4; ++i)
                af[i] = *(const short8*)&As[swz64(wr * 64 + i * 16 + (lane & 15), g)];
#pragma unroll
            for (int j = 0; j < 4; ++j)
                bf_[j] = *(const short8*)&Bs[swz64(wc * 64 + j * 16 + (lane & 15), g)];
#pragma unroll
            for (int i = 0; i < 4; ++i)
#pragma unroll
                for (int j = 0; j < 4; ++j)
                    acc[i][j] = __builtin_amdgcn_mfma_f32_16x16x32_bf16(af[i], bf_[j], acc[i][j], 0, 0, 0);
        }
    }
#pragma unroll
    for (int i = 0; i < 4; ++i)
#pragma unroll
        for (int j = 0; j < 4; ++j) {
            int row = m0 + wr * 64 + i * 16 + (lane >> 4) * 4;
            int col = n0 + wc * 64 + j * 16 + (lane & 15);
            float b = bias[col];
#pragma unroll
            for (int r = 0; r < 4; ++r)
                out[(size_t)(row + r) * dim + col] = acc[i][j][r] + b;
        }
}

extern "C" void kernel_launch(void* const* d_in, const int* in_sizes, int n_in,
                              void* d_out, int out_size, void* d_ws, size_t ws_size,
                              hipStream_t stream) {
    const float* x = (const float*)d_in[0];
    const float* vec = (const float*)d_in[1];
    const float* bias = (const float*)d_in[2];
    float* out = (float*)d_out;

    int dim = in_sizes[2];
    int m = in_sizes[1] / dim;
    int n = in_sizes[0] / dim;

    const size_t MD = (size_t)m * dim;
    const size_t MM = (size_t)m * m;

    char* cur = (char*)d_ws;
    auto alloc_f = [&](size_t nelem) { float* p = (float*)cur; cur += nelem * 4; return p; };
    auto alloc_s = [&](size_t nelem) { short* p = (short*)cur; cur += nelem * 2; return p; };
    float* V   = alloc_f(MD);
    float* G   = alloc_f(MM);
    short* Vh  = alloc_s(MD);
    short* Vl  = alloc_s(MD);
    short* Vth = alloc_s(MD);
    short* Vtl = alloc_s(MD);
    short* Gh  = alloc_s(MM);
    short* Gl  = alloc_s(MM);
    short* Th  = alloc_s(MM);
    short* Tl  = alloc_s(MM);
    short* Tth = alloc_s(MM);
    short* Ttl = alloc_s(MM);
    short* Wh  = alloc_s(MD);
    short* Wl  = alloc_s(MD);
    short* Qt  = alloc_s((size_t)dim * dim);
    short* tmph = alloc_s(MM / 2);
    short* tmpl = alloc_s(MM / 2);
    short* xh  = alloc_s((size_t)n * dim);

    k_normalize<<<m, 256, 0, stream>>>(vec, V, dim);
    k_split<<<1024, 256, 0, stream>>>(V, Vh, Vl, (int)(MD / 4));
    k_tsplit<<<dim3(dim / 32, m / 32), 256, 0, stream>>>(V, Vth, Vtl, m, dim);

    // G = V * V^T, upper-triangle 64-tiles; fp32 + split outputs
    k_nt64p<3, 2><<<dim3(m / 64, m / 64), 256, 0, stream>>>(Vh, Vl, Vh, Vl, G, Gh, Gl,
                                                            dim, dim, dim, m);
    // diag-block inversion -> split T (row-major + transposed)
    k_baseinv2<<<(m / 64) * 16, 256, 0, stream>>>(G, Th, Tl, Tth, Ttl, m);
    // tree levels, all MFMA on split operands
    for (int s = 64; s < m; s <<= 1) {
        dim3 g(s / 64, s / 64, m / (2 * s));
        k_trimm<1><<<g, 256, 0, stream>>>(Gh, Gl, Tth, Ttl, tmph, tmpl, nullptr, nullptr, m, s);
        k_trimm<2><<<g, 256, 0, stream>>>(Th, Tl, tmph, tmpl, Th, Tl, Tth, Ttl, m, s);
    }

    // W[d][k] = sum_{j<=k} Vt[d][j] * Tt[k][j]  (triangular K-bound)
    k_nt64p<1, 1><<<dim3(m / 64, dim / 64), 256, 0, stream>>>(Vth, Vtl, Tth, Ttl, nullptr, Wh, Wl,
                                                              m, m, m, m);
    // Qt[e][d] = delta - sum_k Vt[e][k] * W[d][k]
    k_nt64p<2, 0><<<dim3(dim / 64, dim / 64), 256, 0, stream>>>(Vth, Vtl, Wh, Wl, nullptr, Qt, nullptr,
                                                                m, m, m, dim);

    // xh = bf16(x); out = xh * Qt^T + bias
    k_cast<<<2048, 256, 0, stream>>>(x, xh, (int)((size_t)n * dim / 4));
    k_apply3<<<dim3(dim / 128, n / 128), 256, 0, stream>>>(xh, Qt, bias, out, dim);
}